// Round 3
// baseline (1504.779 us; speedup 1.0000x reference)
//
#include <hip/hip_runtime.h>
#include <stdint.h>

// LatentODE: B=8192, T=100, D=44, NH=64, L=8.
// All three phases in MFMA "transposed orientation": activations [feature x batch(16)],
// weights^T as A-frags, batch = MFMA columns. Layer transitions = within-column lane
// shuffle (no LDS anywhere). Decoder+NLL offloaded to a batch*time-parallel kernel.

constexpr int B_ = 8192, T_ = 100, D_ = 44, NH_ = 64, L_ = 8;

typedef __bf16 bf16x8 __attribute__((ext_vector_type(8)));
typedef float f32x4 __attribute__((ext_vector_type(4)));
typedef uint32_t u32x4 __attribute__((ext_vector_type(4)));

__device__ __forceinline__ float fexp2(float x) { return __builtin_amdgcn_exp2f(x); }
__device__ __forceinline__ float frcp(float x) { return __builtin_amdgcn_rcpf(x); }
__device__ __forceinline__ float fexp(float x) { return fexp2(x * 1.44269504088896341f); }
__device__ __forceinline__ float tanh_f(float x) {
  float e = fexp2(x * 2.88539008177792681f);
  return 1.0f - 2.0f * frcp(e + 1.0f);
}
__device__ __forceinline__ float elu_f(float x) { return x > 0.0f ? x : (fexp(x) - 1.0f); }
__device__ __forceinline__ uint32_t f2bs(float x) {
  return (uint32_t)__builtin_bit_cast(unsigned short, (__bf16)x);
}
__device__ __forceinline__ uint32_t pk(float lo, float hi) { return f2bs(lo) | (f2bs(hi) << 16); }
__device__ __forceinline__ uint32_t sh(uint32_t v, int s) { return (uint32_t)__shfl((int)v, s, 64); }
__device__ __forceinline__ f32x4 mfma16(bf16x8 a, bf16x8 b, f32x4 c) {
  return __builtin_amdgcn_mfma_f32_16x16x32_bf16(a, b, c, 0, 0, 0);
}
__device__ __forceinline__ bf16x8 pack8(float a, float b, float c, float d,
                                        float e, float f, float g, float h) {
  u32x4 u = {pk(a, b), pk(c, d), pk(e, f), pk(g, h)};
  return __builtin_bit_cast(bf16x8, u);
}

// C-layout [64 x 16] (4 tiles, post-activation) -> B-frags for K=64.
// Within-column shuffle: dest lane (q,c) pulls packed dwords from lanes
// 32*(q&1)+c and +16, tile 2ks+(q>>1). 16 shfl + 8 sel + 8 packs, no LDS.
__device__ __forceinline__ void repack64(const f32x4* e, bf16x8* b, int s0, int s1, bool hi) {
  uint32_t P01[4], P23[4];
#pragma unroll
  for (int tau = 0; tau < 4; ++tau) {
    P01[tau] = pk(e[tau][0], e[tau][1]);
    P23[tau] = pk(e[tau][2], e[tau][3]);
  }
#pragma unroll
  for (int ks = 0; ks < 2; ++ks) {
    uint32_t d0a = sh(P01[2 * ks], s0), d0b = sh(P01[2 * ks + 1], s0);
    uint32_t d1a = sh(P23[2 * ks], s0), d1b = sh(P23[2 * ks + 1], s0);
    uint32_t d2a = sh(P01[2 * ks], s1), d2b = sh(P01[2 * ks + 1], s1);
    uint32_t d3a = sh(P23[2 * ks], s1), d3b = sh(P23[2 * ks + 1], s1);
    u32x4 u = {hi ? d0b : d0a, hi ? d1b : d1a, hi ? d2b : d2a, hi ? d3b : d3a};
    b[ks] = __builtin_bit_cast(bf16x8, u);
  }
}

// z (f32x4 C-layout rows 0-7 on lanes<32, zeros elsewhere) -> B-frag (K=32, rows>=8 garbage-ok).
__device__ __forceinline__ bf16x8 build_bz(f32x4 z, int c) {
  uint32_t p01 = pk(z[0], z[1]), p23 = pk(z[2], z[3]);
  u32x4 u = {sh(p01, c), sh(p23, c), sh(p01, c + 16), sh(p23, c + 16)};
  return __builtin_bit_cast(bf16x8, u);
}

// =================== Kernel 1: RNN encoder (MFMA) ===================
__global__ __launch_bounds__(64) void rnn_kernel(
    const float* __restrict__ x, const float* __restrict__ mask,
    const float* __restrict__ eps,
    const float* __restrict__ Wi2h, const float* __restrict__ bi2h,
    const float* __restrict__ Wh2o, const float* __restrict__ bh2o,
    float* __restrict__ z0buf, float* __restrict__ loss) {
  const int lane = threadIdx.x;
  const int c = lane & 15, q = lane >> 4;
  const int r0 = blockIdx.x * 16;
  const int s0 = ((lane & 16) << 1) | c, s1 = s0 + 16;
  const bool hi = lane >= 32;

  // A-frags of Wi2h^T with state order [h(0..63); obs(64..107)]; k>=108 zero.
  bf16x8 Ai[4][4];
#pragma unroll
  for (int tau = 0; tau < 4; ++tau)
#pragma unroll
    for (int ks = 0; ks < 4; ++ks) {
      bf16x8 f;
      const int m = 16 * tau + c;
#pragma unroll
      for (int i = 0; i < 8; ++i) {
        const int k = 32 * ks + 8 * q + i;
        float v = 0.0f;
        if (k < 64) v = Wi2h[(44 + k) * 64 + m];
        else if (k < 108) v = Wi2h[(k - 64) * 64 + m];
        f[i] = (__bf16)v;
      }
      Ai[tau][ks] = f;
    }
  bf16x8 Ah2o[2];
#pragma unroll
  for (int ks = 0; ks < 2; ++ks) {
    bf16x8 f;
#pragma unroll
    for (int i = 0; i < 8; ++i) f[i] = (__bf16)Wh2o[(32 * ks + 8 * q + i) * 16 + c];
    Ah2o[ks] = f;
  }
  f32x4 bi_[4];
#pragma unroll
  for (int tau = 0; tau < 4; ++tau)
#pragma unroll
    for (int r = 0; r < 4; ++r) bi_[tau][r] = bi2h[16 * tau + 4 * q + r];
  f32x4 bo;
#pragma unroll
  for (int r = 0; r < 4; ++r) bo[r] = bh2o[4 * q + r];

  const size_t rowstep = (size_t)D_;
  const float* xrowbase = x + (size_t)(r0 + c) * T_ * D_;
  const float* mrowbase = mask + (size_t)(r0 + c) * T_ * D_;

  auto load_obs = [&](int t, float4& a0, float4& a1, float4& b0, float4& b1,
                      float4& ma0, float4& ma1, float4& mb0, float4& mb1) {
    const float4* xr = (const float4*)(xrowbase + (size_t)t * rowstep);
    const float4* mr = (const float4*)(mrowbase + (size_t)t * rowstep);
    a0 = xr[2 * q]; a1 = xr[2 * q + 1]; ma0 = mr[2 * q]; ma1 = mr[2 * q + 1];
    float4 zz = {0.f, 0.f, 0.f, 0.f};
    b0 = zz; b1 = zz; mb0 = zz; mb1 = zz;
    if (q == 0) { b0 = xr[8]; b1 = xr[9]; mb0 = mr[8]; mb1 = mr[9]; }
    else if (q == 1) { b0 = xr[10]; mb0 = mr[10]; }
  };

  f32x4 hc[4] = {};  // h in C-layout (rows 0..63), f32
  float4 a0, a1, b0, b1, ma0, ma1, mb0, mb1;
  load_obs(T_ - 1, a0, a1, b0, b1, ma0, ma1, mb0, mb1);

#pragma unroll 1
  for (int s = 0; s < T_; ++s) {
    const int t = T_ - 1 - s;
    float4 ca0 = a0, ca1 = a1, cb0 = b0, cb1 = b1;
    float4 cm0 = ma0, cm1 = ma1, cn0 = mb0, cn1 = mb1;
    if (t > 0) load_obs(t - 1, a0, a1, b0, b1, ma0, ma1, mb0, mb1);  // prefetch

    bf16x8 bh[2];
    repack64(hc, bh, s0, s1, hi);
    f32x4 acc[4];
#pragma unroll
    for (int tau = 0; tau < 4; ++tau)
      acc[tau] = mfma16(Ai[tau][1], bh[1], mfma16(Ai[tau][0], bh[0], bi_[tau]));

    bf16x8 o2 = pack8(ca0.x * cm0.x, ca0.y * cm0.y, ca0.z * cm0.z, ca0.w * cm0.w,
                      ca1.x * cm1.x, ca1.y * cm1.y, ca1.z * cm1.z, ca1.w * cm1.w);
    bf16x8 o3 = pack8(cb0.x * cn0.x, cb0.y * cn0.y, cb0.z * cn0.z, cb0.w * cn0.w,
                      cb1.x * cn1.x, cb1.y * cn1.y, cb1.z * cn1.z, cb1.w * cn1.w);
#pragma unroll
    for (int tau = 0; tau < 4; ++tau) {
      acc[tau] = mfma16(Ai[tau][3], o3, mfma16(Ai[tau][2], o2, acc[tau]));
#pragma unroll
      for (int r = 0; r < 4; ++r) hc[tau][r] = tanh_f(acc[tau][r]);
    }
  }

  // out = Wh2o^T h + b : [16 x 16], rows 0-7 mean, 8-15 logvar.
  bf16x8 bh[2];
  repack64(hc, bh, s0, s1, hi);
  f32x4 o = mfma16(Ah2o[1], bh[1], mfma16(Ah2o[0], bh[0], bo));

  float lv[4];
#pragma unroll
  for (int r = 0; r < 4; ++r)
    lv[r] = __int_as_float(__shfl(__float_as_int(o[r]), lane + 32, 64));

  float klt = 0.0f;
  if (q < 2) {
    const float4 ev = *(const float4*)(eps + (size_t)(r0 + c) * 8 + 4 * q);
    float z0v[4];
    const float e4[4] = {ev.x, ev.y, ev.z, ev.w};
#pragma unroll
    for (int r = 0; r < 4; ++r) {
      const float m = o[r];
      z0v[r] = e4[r] * fexp(0.5f * lv[r]) + m;
      klt += -0.5f * lv[r] + (fexp(lv[r]) + m * m) * 0.5f - 0.5f;
    }
    float4 st = {z0v[0], z0v[1], z0v[2], z0v[3]};
    *(float4*)(z0buf + (size_t)(r0 + c) * 8 + 4 * q) = st;
  }
  klt += __shfl_xor(klt, 1);  klt += __shfl_xor(klt, 2);
  klt += __shfl_xor(klt, 4);  klt += __shfl_xor(klt, 8);
  klt += __shfl_xor(klt, 16); klt += __shfl_xor(klt, 32);
  if (lane == 0) atomicAdd(loss, klt * (1.0f / (float)B_));
}

// =================== Kernel 2: sequential RK4 (fevals only) ===================
__global__ __launch_bounds__(64) void rk4_kernel(
    const float* __restrict__ z0buf, uint16_t* __restrict__ ztraj,
    const float* __restrict__ Wf1, const float* __restrict__ bf1,
    const float* __restrict__ Wf2, const float* __restrict__ bf2,
    const float* __restrict__ Wf3, const float* __restrict__ bf3) {
  const int lane = threadIdx.x;
  const int c = lane & 15, q = lane >> 4;
  const int r0 = blockIdx.x * 16;
  const int s0 = ((lane & 16) << 1) | c, s1 = s0 + 16;
  const bool hi = lane >= 32;

  bf16x8 A1[4], A2[4][2], A3[2];
#pragma unroll
  for (int tau = 0; tau < 4; ++tau) {
    bf16x8 f;
#pragma unroll
    for (int i = 0; i < 8; ++i) {
      const int k = 8 * q + i;
      f[i] = (__bf16)((k < 8) ? Wf1[k * 64 + 16 * tau + c] : 0.0f);
    }
    A1[tau] = f;
#pragma unroll
    for (int ks = 0; ks < 2; ++ks) {
      bf16x8 g;
#pragma unroll
      for (int i = 0; i < 8; ++i) g[i] = (__bf16)Wf2[(32 * ks + 8 * q + i) * 64 + 16 * tau + c];
      A2[tau][ks] = g;
    }
  }
#pragma unroll
  for (int ks = 0; ks < 2; ++ks) {
    bf16x8 f;
#pragma unroll
    for (int i = 0; i < 8; ++i)
      f[i] = (__bf16)((c < 8) ? Wf3[(32 * ks + 8 * q + i) * 8 + c] : 0.0f);
    A3[ks] = f;
  }
  f32x4 b1_[4], b2_[4], b3_;
#pragma unroll
  for (int tau = 0; tau < 4; ++tau)
#pragma unroll
    for (int r = 0; r < 4; ++r) {
      b1_[tau][r] = bf1[16 * tau + 4 * q + r];
      b2_[tau][r] = bf2[16 * tau + 4 * q + r];
    }
#pragma unroll
  for (int r = 0; r < 4; ++r) b3_[r] = (q < 2) ? bf3[4 * q + r] : 0.0f;

  f32x4 z = {};
  if (q < 2) {
    const float4 zi = *(const float4*)(z0buf + (size_t)(r0 + c) * 8 + 4 * q);
    z[0] = zi.x; z[1] = zi.y; z[2] = zi.z; z[3] = zi.w;
  }

  auto feval = [&](bf16x8 bz) -> f32x4 {
    f32x4 h[4];
#pragma unroll
    for (int tau = 0; tau < 4; ++tau) {
      h[tau] = mfma16(A1[tau], bz, b1_[tau]);
#pragma unroll
      for (int r = 0; r < 4; ++r) h[tau][r] = elu_f(h[tau][r]);
    }
    bf16x8 bh[2];
    repack64(h, bh, s0, s1, hi);
    f32x4 g[4];
#pragma unroll
    for (int tau = 0; tau < 4; ++tau) {
      g[tau] = mfma16(A2[tau][1], bh[1], mfma16(A2[tau][0], bh[0], b2_[tau]));
#pragma unroll
      for (int r = 0; r < 4; ++r) g[tau][r] = elu_f(g[tau][r]);
    }
    bf16x8 bg[2];
    repack64(g, bg, s0, s1, hi);
    return mfma16(A3[1], bg[1], mfma16(A3[0], bg[0], b3_));
  };

  const float dt = 1.0f / (float)(T_ - 1);
  const float hdt = 0.5f * dt;

#pragma unroll 1
  for (int t = 0; t < T_; ++t) {
    if (lane < 32) {  // store z_t as bf16 row [8] for the decoder
      uint2 st;
      st.x = pk(z[0], z[1]); st.y = pk(z[2], z[3]);
      *(uint2*)(ztraj + ((size_t)(r0 + c) * T_ + t) * 8 + 4 * q) = st;
    }
    if (t == T_ - 1) break;

    f32x4 k1 = feval(build_bz(z, c));
    f32x4 zt;
#pragma unroll
    for (int r = 0; r < 4; ++r) zt[r] = z[r] + hdt * k1[r];
    f32x4 k2 = feval(build_bz(zt, c));
#pragma unroll
    for (int r = 0; r < 4; ++r) zt[r] = z[r] + hdt * k2[r];
    f32x4 k3 = feval(build_bz(zt, c));
#pragma unroll
    for (int r = 0; r < 4; ++r) zt[r] = z[r] + dt * k3[r];
    f32x4 k4 = feval(build_bz(zt, c));
#pragma unroll
    for (int r = 0; r < 4; ++r)
      z[r] += (dt / 6.0f) * (k1[r] + 2.0f * (k2[r] + k3[r]) + k4[r]);
  }
}

// =================== Kernel 3: parallel decoder + masked NLL ===================
__global__ __launch_bounds__(256) void dec_kernel(
    const float* __restrict__ x, const float* __restrict__ mask,
    const uint16_t* __restrict__ ztraj,
    const float* __restrict__ Wd1, const float* __restrict__ bd1,
    const float* __restrict__ Wd2, const float* __restrict__ bd2,
    float* __restrict__ loss) {
  const int lane = threadIdx.x & 63;
  const int wave = threadIdx.x >> 6;
  const int c = lane & 15, q = lane >> 4;
  const int bt0 = (blockIdx.x * 4 + wave) * 16;
  const int s0 = ((lane & 16) << 1) | c, s1 = s0 + 16;
  const bool hi = lane >= 32;

  bf16x8 Ad1[4], Ad2[3][2];
#pragma unroll
  for (int tau = 0; tau < 4; ++tau) {
    bf16x8 f;
#pragma unroll
    for (int i = 0; i < 8; ++i) {
      const int k = 8 * q + i;
      f[i] = (__bf16)((k < 8) ? Wd1[k * 64 + 16 * tau + c] : 0.0f);
    }
    Ad1[tau] = f;
  }
#pragma unroll
  for (int tau = 0; tau < 3; ++tau)
#pragma unroll
    for (int ks = 0; ks < 2; ++ks) {
      bf16x8 f;
      const int m = 16 * tau + c;
#pragma unroll
      for (int i = 0; i < 8; ++i)
        f[i] = (__bf16)((m < 44) ? Wd2[(32 * ks + 8 * q + i) * 44 + m] : 0.0f);
      Ad2[tau][ks] = f;
    }
  f32x4 bd1_[4], bd2_[3];
#pragma unroll
  for (int tau = 0; tau < 4; ++tau)
#pragma unroll
    for (int r = 0; r < 4; ++r) bd1_[tau][r] = bd1[16 * tau + 4 * q + r];
#pragma unroll
  for (int tau = 0; tau < 3; ++tau)
#pragma unroll
    for (int r = 0; r < 4; ++r) {
      const int d = 16 * tau + 4 * q + r;
      bd2_[tau][r] = (d < 44) ? bd2[d] : 0.0f;
    }

  // z B-frag: each lane loads full bf16 row (bt0+c) = exactly the frag dwords.
  const u32x4 zu = *(const u32x4*)(ztraj + (size_t)(bt0 + c) * 8);
  const bf16x8 bz = __builtin_bit_cast(bf16x8, zu);

  f32x4 hd[4];
#pragma unroll
  for (int tau = 0; tau < 4; ++tau) {
    hd[tau] = mfma16(Ad1[tau], bz, bd1_[tau]);
#pragma unroll
    for (int r = 0; r < 4; ++r) hd[tau][r] = fmaxf(hd[tau][r], 0.0f);
  }
  bf16x8 bh[2];
  repack64(hd, bh, s0, s1, hi);

  float qacc = 0.0f;
#pragma unroll
  for (int tau = 0; tau < 3; ++tau) {
    f32x4 p = mfma16(Ad2[tau][1], bh[1], mfma16(Ad2[tau][0], bh[0], bd2_[tau]));
    const int d0 = 16 * tau + 4 * q;
    if (d0 < 44) {
      const size_t base = (size_t)(bt0 + c) * D_ + d0;
      const float4 xv = *(const float4*)(x + base);
      const float4 mv = *(const float4*)(mask + base);
      const float xa[4] = {xv.x, xv.y, xv.z, xv.w};
      const float ma[4] = {mv.x, mv.y, mv.z, mv.w};
#pragma unroll
      for (int r = 0; r < 4; ++r) {
        const float mx = xa[r] * ma[r];
        const float upd = (mx != 0.0f) ? mx : p[r];
        const float df = xa[r] - upd;
        qacc += df * df;
      }
    }
  }
  qacc += __shfl_xor(qacc, 1);  qacc += __shfl_xor(qacc, 2);
  qacc += __shfl_xor(qacc, 4);  qacc += __shfl_xor(qacc, 8);
  qacc += __shfl_xor(qacc, 16); qacc += __shfl_xor(qacc, 32);
  if (lane == 0) {
    const float c0 = 0.28503427112126353f;  // -0.5*(log(2pi)+2*log(0.3))
    const float contrib = qacc * (0.5f / 0.09f) - 16.0f * (float)D_ * c0;
    atomicAdd(loss, contrib * (1.0f / (float)B_));
  }
}

extern "C" void kernel_launch(void* const* d_in, const int* in_sizes, int n_in,
                              void* d_out, int out_size, void* d_ws, size_t ws_size,
                              hipStream_t stream) {
  const float* x    = (const float*)d_in[0];
  const float* mask = (const float*)d_in[1];
  const float* eps  = (const float*)d_in[2];
  const float* Wi2h = (const float*)d_in[3];
  const float* bi2h = (const float*)d_in[4];
  const float* Wh2o = (const float*)d_in[5];
  const float* bh2o = (const float*)d_in[6];
  const float* Wf1  = (const float*)d_in[7];
  const float* bf1  = (const float*)d_in[8];
  const float* Wf2  = (const float*)d_in[9];
  const float* bf2  = (const float*)d_in[10];
  const float* Wf3  = (const float*)d_in[11];
  const float* bf3  = (const float*)d_in[12];
  const float* Wd1  = (const float*)d_in[13];
  const float* bd1  = (const float*)d_in[14];
  const float* Wd2  = (const float*)d_in[15];
  const float* bd2  = (const float*)d_in[16];

  float* loss = (float*)d_out;
  float* z0buf = (float*)d_ws;                               // 256 KB
  uint16_t* ztraj = (uint16_t*)((char*)d_ws + (size_t)B_ * L_ * 4);  // 13.1 MB bf16

  hipMemsetAsync(loss, 0, sizeof(float), stream);

  rnn_kernel<<<dim3(B_ / 16), dim3(64), 0, stream>>>(
      x, mask, eps, Wi2h, bi2h, Wh2o, bh2o, z0buf, loss);
  rk4_kernel<<<dim3(B_ / 16), dim3(64), 0, stream>>>(
      z0buf, ztraj, Wf1, bf1, Wf2, bf2, Wf3, bf3);
  dec_kernel<<<dim3(B_ * T_ / 64), dim3(256), 0, stream>>>(
      x, mask, ztraj, Wd1, bd1, Wd2, bd2, loss);
}

// Round 4
// 825.238 us; speedup vs baseline: 1.8234x; 1.8234x over previous
//
#include <hip/hip_runtime.h>
#include <stdint.h>

// LatentODE fused: B=8192, T=100, D=44, NH=64, L=8.
// ONE kernel per 16-batch tile (512 waves): backward RNN scan -> z0/KL ->
// forward RK4 + fused decoder + masked NLL, all in registers. Layer
// transposes via per-wave LDS round-trip (4 ds_write_b64 + 2 ds_read_b128,
// in-order DS pipe, no barriers). Biases ride spare K-rows of the A-frags.
// Per-wave partials -> tiny reduce kernel (no same-address atomics).

constexpr int B_ = 8192, T_ = 100, D_ = 44, NH_ = 64, L_ = 8;

typedef __bf16 bf16x8 __attribute__((ext_vector_type(8)));
typedef float f32x4 __attribute__((ext_vector_type(4)));
typedef uint32_t u32x4 __attribute__((ext_vector_type(4)));
typedef uint32_t u32x2 __attribute__((ext_vector_type(2)));

__device__ __forceinline__ float fexp2(float x) { return __builtin_amdgcn_exp2f(x); }
__device__ __forceinline__ float frcp(float x) { return __builtin_amdgcn_rcpf(x); }
__device__ __forceinline__ float fexp(float x) { return fexp2(x * 1.44269504088896341f); }
__device__ __forceinline__ float tanh_f(float x) {
  float e = fexp2(x * 2.88539008177792681f);
  return 1.0f - 2.0f * frcp(e + 1.0f);
}
__device__ __forceinline__ float elu_f(float x) { return x > 0.0f ? x : (fexp(x) - 1.0f); }
__device__ __forceinline__ uint32_t f2bs(float x) {
  return (uint32_t)__builtin_bit_cast(unsigned short, (__bf16)x);
}
__device__ __forceinline__ uint32_t pk(float lo, float hi) { return f2bs(lo) | (f2bs(hi) << 16); }
__device__ __forceinline__ uint32_t sh(uint32_t v, int s) { return (uint32_t)__shfl((int)v, s, 64); }
__device__ __forceinline__ f32x4 mfma16(bf16x8 a, bf16x8 b, f32x4 c) {
  return __builtin_amdgcn_mfma_f32_16x16x32_bf16(a, b, c, 0, 0, 0);
}
__device__ __forceinline__ bf16x8 pack8(float a, float b, float c, float d,
                                        float e, float f, float g, float h) {
  u32x4 u = {pk(a, b), pk(c, d), pk(e, f), pk(g, h)};
  return __builtin_bit_cast(bf16x8, u);
}
__device__ __forceinline__ float f4get(const float4& f, int i) {
  return i == 0 ? f.x : (i == 1 ? f.y : (i == 2 ? f.z : f.w));
}

// C-layout [64 x 16] (f32, 4 tiles) -> 2 B-frags (K=64) via per-wave LDS.
// LDS layout: word = 36*col + kpair (kpair = row/2). Writes: consecutive pair
// -> ds_write_b64; reads: 4 consecutive kpairs -> ds_read_b128 (16B aligned).
// Bank math: writes 2-way (free), reads uniform 8-deep (minimum). No barriers:
// single-wave in-order DS pipe.
__device__ __forceinline__ void repack_lds(uint32_t* tb, int c, int q,
                                           const f32x4* e, bf16x8* bh) {
#pragma unroll
  for (int tau = 0; tau < 4; ++tau) {
    u32x2 w = {pk(e[tau][0], e[tau][1]), pk(e[tau][2], e[tau][3])};
    *(u32x2*)(tb + 36 * c + 8 * tau + 2 * q) = w;
  }
#pragma unroll
  for (int ks = 0; ks < 2; ++ks) {
    u32x4 r = *(const u32x4*)(tb + 36 * c + 16 * ks + 4 * q);
    bh[ks] = __builtin_bit_cast(bf16x8, r);
  }
}

// z (C-layout f32, rows 0-7 on lanes q<2) -> B-frag; row 8 := 1.0 (bias row).
__device__ __forceinline__ bf16x8 build_bz(f32x4 z, int c, int q) {
  uint32_t p01 = pk(z[0], z[1]), p23 = pk(z[2], z[3]);
  u32x4 u = {sh(p01, c), sh(p23, c), sh(p01, c + 16), sh(p23, c + 16)};
  if (q == 1) u[0] = 0x3f80u;  // k=8 -> 1.0, k=9 -> 0
  return __builtin_bit_cast(bf16x8, u);
}

__global__ __launch_bounds__(64) void fused_kernel(
    const float* __restrict__ x, const float* __restrict__ mask,
    const float* __restrict__ eps,
    const float* __restrict__ Wi2h, const float* __restrict__ bi2h,
    const float* __restrict__ Wh2o, const float* __restrict__ bh2o,
    const float* __restrict__ Wf1, const float* __restrict__ bf1,
    const float* __restrict__ Wf2, const float* __restrict__ bf2,
    const float* __restrict__ Wf3, const float* __restrict__ bf3,
    const float* __restrict__ Wd1, const float* __restrict__ bd1,
    const float* __restrict__ Wd2, const float* __restrict__ bd2,
    float* __restrict__ part) {
  const int lane = threadIdx.x;
  const int c = lane & 15, q = lane >> 4;
  const int r0 = blockIdx.x * 16;

  __shared__ uint32_t tbufA[576];  // feval transposes
  __shared__ uint32_t tbufB[576];  // decoder transposes

  // ================= Phase 1: backward RNN scan =================
  // State rows: [h 0..63 ; obs 64..107 ; bias 108]. Bias at k=108.
  bf16x8 Ai[4][4];
#pragma unroll
  for (int tau = 0; tau < 4; ++tau)
#pragma unroll
    for (int ks = 0; ks < 4; ++ks) {
      bf16x8 f;
      const int m = 16 * tau + c;
#pragma unroll
      for (int i = 0; i < 8; ++i) {
        const int k = 32 * ks + 8 * q + i;
        float v = 0.0f;
        if (k < 64) v = Wi2h[(44 + k) * 64 + m];
        else if (k < 108) v = Wi2h[(k - 64) * 64 + m];
        else if (k == 108) v = bi2h[m];
        f[i] = (__bf16)v;
      }
      Ai[tau][ks] = f;
    }
  bf16x8 Ah2o[2];
#pragma unroll
  for (int ks = 0; ks < 2; ++ks) {
    bf16x8 f;
#pragma unroll
    for (int i = 0; i < 8; ++i) f[i] = (__bf16)Wh2o[(32 * ks + 8 * q + i) * 16 + c];
    Ah2o[ks] = f;
  }
  f32x4 bo;
#pragma unroll
  for (int r = 0; r < 4; ++r) bo[r] = bh2o[4 * q + r];

  const float* xrowbase = x + (size_t)(r0 + c) * T_ * D_;
  const float* mrowbase = mask + (size_t)(r0 + c) * T_ * D_;

  auto load_obs = [&](int t, float4& a0, float4& a1, float4& b0, float4& b1,
                      float4& ma0, float4& ma1, float4& mb0, float4& mb1) {
    const float4* xr = (const float4*)(xrowbase + (size_t)t * D_);
    const float4* mr = (const float4*)(mrowbase + (size_t)t * D_);
    a0 = xr[2 * q]; a1 = xr[2 * q + 1]; ma0 = mr[2 * q]; ma1 = mr[2 * q + 1];
    float4 zz = {0.f, 0.f, 0.f, 0.f};
    b0 = zz; b1 = zz; mb0 = zz; mb1 = zz;
    if (q == 0) { b0 = xr[8]; b1 = xr[9]; mb0 = mr[8]; mb1 = mr[9]; }
    else if (q == 1) { b0 = xr[10]; mb0 = mr[10]; }
  };

  f32x4 hc[4] = {};
  float4 a0, a1, b0, b1, ma0, ma1, mb0, mb1;
  load_obs(T_ - 1, a0, a1, b0, b1, ma0, ma1, mb0, mb1);

#pragma unroll 1
  for (int s = 0; s < T_; ++s) {
    const int t = T_ - 1 - s;
    float4 ca0 = a0, ca1 = a1, cb0 = b0, cb1 = b1;
    float4 cm0 = ma0, cm1 = ma1, cn0 = mb0, cn1 = mb1;
    if (t > 0) load_obs(t - 1, a0, a1, b0, b1, ma0, ma1, mb0, mb1);

    bf16x8 bh[2];
    repack_lds(tbufA, c, q, hc, bh);
    bf16x8 o2 = pack8(ca0.x * cm0.x, ca0.y * cm0.y, ca0.z * cm0.z, ca0.w * cm0.w,
                      ca1.x * cm1.x, ca1.y * cm1.y, ca1.z * cm1.z, ca1.w * cm1.w);
    const float e44 = (q == 1) ? 1.0f : cb1.x * cn1.x;  // bias row k=108
    bf16x8 o3 = pack8(cb0.x * cn0.x, cb0.y * cn0.y, cb0.z * cn0.z, cb0.w * cn0.w,
                      e44, cb1.y * cn1.y, cb1.z * cn1.z, cb1.w * cn1.w);
#pragma unroll
    for (int tau = 0; tau < 4; ++tau) {
      f32x4 zero = {0.f, 0.f, 0.f, 0.f};
      f32x4 acc = mfma16(Ai[tau][0], bh[0], zero);
      acc = mfma16(Ai[tau][1], bh[1], acc);
      acc = mfma16(Ai[tau][2], o2, acc);
      acc = mfma16(Ai[tau][3], o3, acc);
#pragma unroll
      for (int r = 0; r < 4; ++r) hc[tau][r] = tanh_f(acc[r]);
    }
  }

  // ================= Phase 2: head, z0, KL =================
  bf16x8 bhF[2];
  repack_lds(tbufA, c, q, hc, bhF);
  f32x4 o = mfma16(Ah2o[1], bhF[1], mfma16(Ah2o[0], bhF[0], bo));

  float lv[4];
#pragma unroll
  for (int r = 0; r < 4; ++r)
    lv[r] = __int_as_float(__shfl(__float_as_int(o[r]), lane + 32, 64));

  float klt = 0.0f;
  f32x4 z = {};
  if (q < 2) {
    const float4 ev = *(const float4*)(eps + (size_t)(r0 + c) * 8 + 4 * q);
#pragma unroll
    for (int r = 0; r < 4; ++r) {
      const float m = o[r];
      z[r] = f4get(ev, r) * fexp(0.5f * lv[r]) + m;
      klt += -0.5f * lv[r] + (fexp(lv[r]) + m * m) * 0.5f - 0.5f;
    }
  }
  klt += __shfl_xor(klt, 1);  klt += __shfl_xor(klt, 2);
  klt += __shfl_xor(klt, 4);  klt += __shfl_xor(klt, 8);
  klt += __shfl_xor(klt, 16); klt += __shfl_xor(klt, 32);

  __builtin_amdgcn_sched_barrier(0);  // keep phase-3 weight loads below

  // ================= Phase 3: RK4 + fused decoder + NLL =================
  // f-net frags (bias of layer1 at k=8; layers 2/3 bias via acc init).
  bf16x8 A1[4], A2[4][2], A3[2], Ad1[4], Ad2[3][2];
#pragma unroll
  for (int tau = 0; tau < 4; ++tau) {
    bf16x8 f1, fd;
#pragma unroll
    for (int i = 0; i < 8; ++i) {
      const int k = 8 * q + i;
      f1[i] = (__bf16)(k < 8 ? Wf1[k * 64 + 16 * tau + c] : (k == 8 ? bf1[16 * tau + c] : 0.0f));
      fd[i] = (__bf16)(k < 8 ? Wd1[k * 64 + 16 * tau + c] : (k == 8 ? bd1[16 * tau + c] : 0.0f));
    }
    A1[tau] = f1; Ad1[tau] = fd;
#pragma unroll
    for (int ks = 0; ks < 2; ++ks) {
      bf16x8 g;
#pragma unroll
      for (int i = 0; i < 8; ++i) g[i] = (__bf16)Wf2[(32 * ks + 8 * q + i) * 64 + 16 * tau + c];
      A2[tau][ks] = g;
    }
  }
#pragma unroll
  for (int ks = 0; ks < 2; ++ks) {
    bf16x8 f;
#pragma unroll
    for (int i = 0; i < 8; ++i)
      f[i] = (__bf16)((c < 8) ? Wf3[(32 * ks + 8 * q + i) * 8 + c] : 0.0f);
    A3[ks] = f;
  }
#pragma unroll
  for (int tau = 0; tau < 3; ++tau)
#pragma unroll
    for (int ks = 0; ks < 2; ++ks) {
      bf16x8 f;
      const int m = 16 * tau + c;
#pragma unroll
      for (int i = 0; i < 8; ++i)
        f[i] = (__bf16)((m < 44) ? Wd2[(32 * ks + 8 * q + i) * 44 + m] : 0.0f);
      Ad2[tau][ks] = f;
    }
  f32x4 b2_[4], b3_, bd2_[3];
#pragma unroll
  for (int tau = 0; tau < 4; ++tau)
#pragma unroll
    for (int r = 0; r < 4; ++r) b2_[tau][r] = bf2[16 * tau + 4 * q + r];
#pragma unroll
  for (int r = 0; r < 4; ++r) b3_[r] = (q < 2) ? bf3[4 * q + r] : 0.0f;
#pragma unroll
  for (int tau = 0; tau < 3; ++tau)
#pragma unroll
    for (int r = 0; r < 4; ++r) {
      const int d = 16 * tau + 4 * q + r;
      bd2_[tau][r] = (d < 44) ? bd2[d] : 0.0f;
    }

  auto feval = [&](bf16x8 bz) -> f32x4 {
    f32x4 h[4];
#pragma unroll
    for (int tau = 0; tau < 4; ++tau) {
      f32x4 zero = {0.f, 0.f, 0.f, 0.f};
      h[tau] = mfma16(A1[tau], bz, zero);
#pragma unroll
      for (int r = 0; r < 4; ++r) h[tau][r] = elu_f(h[tau][r]);
    }
    bf16x8 bh[2];
    repack_lds(tbufA, c, q, h, bh);
    f32x4 g[4];
#pragma unroll
    for (int tau = 0; tau < 4; ++tau) {
      g[tau] = mfma16(A2[tau][1], bh[1], mfma16(A2[tau][0], bh[0], b2_[tau]));
#pragma unroll
      for (int r = 0; r < 4; ++r) g[tau][r] = elu_f(g[tau][r]);
    }
    bf16x8 bg[2];
    repack_lds(tbufA, c, q, g, bg);
    return mfma16(A3[1], bg[1], mfma16(A3[0], bg[0], b3_));
  };

  auto load_xm = [&](int t, float4* xv, float4* mv) {
#pragma unroll
    for (int tau = 0; tau < 3; ++tau) {
      const int d0 = 16 * tau + 4 * q;
      if (d0 < 44) {
        const size_t off = (size_t)(r0 + c) * T_ * D_ + (size_t)t * D_ + d0;
        xv[tau] = *(const float4*)(x + off);
        mv[tau] = *(const float4*)(mask + off);
      }
    }
  };

  const float dt = 1.0f / (float)(T_ - 1);
  const float hdt = 0.5f * dt;
  float qacc = 0.0f;

  float4 xc[3], mc[3], xn[3], mn[3];
  load_xm(0, xc, mc);

#pragma unroll 1
  for (int t = 0; t < T_; ++t) {
    if (t < T_ - 1) load_xm(t + 1, xn, mn);  // prefetch next step

    bf16x8 bz = build_bz(z, c, q);

    // ---- decoder on z_t (independent chain; interleaves with fevals) ----
    f32x4 hd[4];
#pragma unroll
    for (int tau = 0; tau < 4; ++tau) {
      f32x4 zero = {0.f, 0.f, 0.f, 0.f};
      hd[tau] = mfma16(Ad1[tau], bz, zero);
#pragma unroll
      for (int r = 0; r < 4; ++r) hd[tau][r] = fmaxf(hd[tau][r], 0.0f);
    }
    bf16x8 bhd[2];
    repack_lds(tbufB, c, q, hd, bhd);
#pragma unroll
    for (int tau = 0; tau < 3; ++tau) {
      f32x4 p = mfma16(Ad2[tau][1], bhd[1], mfma16(Ad2[tau][0], bhd[0], bd2_[tau]));
      if (16 * tau + 4 * q < 44) {
#pragma unroll
        for (int r = 0; r < 4; ++r) {
          const float xa = f4get(xc[tau], r), ma = f4get(mc[tau], r);
          const float mx = xa * ma;
          const float upd = (mx != 0.0f) ? mx : p[r];
          const float df = xa - upd;
          qacc += df * df;
        }
      }
    }

    // ---- RK4 advance ----
    if (t < T_ - 1) {
      f32x4 k1 = feval(bz);
      f32x4 zt;
#pragma unroll
      for (int r = 0; r < 4; ++r) zt[r] = z[r] + hdt * k1[r];
      f32x4 k2 = feval(build_bz(zt, c, q));
#pragma unroll
      for (int r = 0; r < 4; ++r) zt[r] = z[r] + hdt * k2[r];
      f32x4 k3 = feval(build_bz(zt, c, q));
#pragma unroll
      for (int r = 0; r < 4; ++r) zt[r] = z[r] + dt * k3[r];
      f32x4 k4 = feval(build_bz(zt, c, q));
#pragma unroll
      for (int r = 0; r < 4; ++r)
        z[r] += (dt / 6.0f) * (k1[r] + 2.0f * (k2[r] + k3[r]) + k4[r]);
#pragma unroll
      for (int tau = 0; tau < 3; ++tau) { xc[tau] = xn[tau]; mc[tau] = mn[tau]; }
    }
  }

  // ---- per-wave partial: kl + scaled SSE ----
  float tot = qacc * (0.5f / 0.09f);
  tot += __shfl_xor(tot, 1);  tot += __shfl_xor(tot, 2);
  tot += __shfl_xor(tot, 4);  tot += __shfl_xor(tot, 8);
  tot += __shfl_xor(tot, 16); tot += __shfl_xor(tot, 32);
  if (lane == 0) part[blockIdx.x] = tot + klt;
}

// =================== final reduction: 512 partials -> loss ===================
__global__ __launch_bounds__(512) void reduce_kernel(const float* __restrict__ part,
                                                     float* __restrict__ out) {
  __shared__ float s[8];
  const int tid = threadIdx.x;
  float v = part[tid];
  v += __shfl_xor(v, 1);  v += __shfl_xor(v, 2);
  v += __shfl_xor(v, 4);  v += __shfl_xor(v, 8);
  v += __shfl_xor(v, 16); v += __shfl_xor(v, 32);
  if ((tid & 63) == 0) s[tid >> 6] = v;
  __syncthreads();
  if (tid == 0) {
    float acc = 0.0f;
#pragma unroll
    for (int i = 0; i < 8; ++i) acc += s[i];
    const float c0 = 0.28503427112126353f;  // -0.5*(log(2pi)+2*log(0.3))
    out[0] = acc * (1.0f / (float)B_) - (float)(T_ * D_) * c0;
  }
}

extern "C" void kernel_launch(void* const* d_in, const int* in_sizes, int n_in,
                              void* d_out, int out_size, void* d_ws, size_t ws_size,
                              hipStream_t stream) {
  const float* x    = (const float*)d_in[0];
  const float* mask = (const float*)d_in[1];
  const float* eps  = (const float*)d_in[2];
  const float* Wi2h = (const float*)d_in[3];
  const float* bi2h = (const float*)d_in[4];
  const float* Wh2o = (const float*)d_in[5];
  const float* bh2o = (const float*)d_in[6];
  const float* Wf1  = (const float*)d_in[7];
  const float* bf1  = (const float*)d_in[8];
  const float* Wf2  = (const float*)d_in[9];
  const float* bf2  = (const float*)d_in[10];
  const float* Wf3  = (const float*)d_in[11];
  const float* bf3  = (const float*)d_in[12];
  const float* Wd1  = (const float*)d_in[13];
  const float* bd1  = (const float*)d_in[14];
  const float* Wd2  = (const float*)d_in[15];
  const float* bd2  = (const float*)d_in[16];

  float* loss = (float*)d_out;
  float* part = (float*)d_ws;  // 512 floats

  fused_kernel<<<dim3(B_ / 16), dim3(64), 0, stream>>>(
      x, mask, eps, Wi2h, bi2h, Wh2o, bh2o, Wf1, bf1, Wf2, bf2, Wf3, bf3,
      Wd1, bd1, Wd2, bd2, part);
  reduce_kernel<<<dim3(1), dim3(512), 0, stream>>>(part, loss);
}